// Round 1
// baseline (271.007 us; speedup 1.0000x reference)
//
#include <hip/hip_runtime.h>
#include <hip/hip_bf16.h>
#include <math.h>

#define N_ATOM   100000
#define N_QUERY  20000
#define KNN      32
#define E_EDGES  (N_QUERY*KNN)
#define HID      128

typedef __attribute__((ext_vector_type(8))) short  short8;
typedef __attribute__((ext_vector_type(4))) float  floatx4;

static __device__ __forceinline__ unsigned short f2bf_bits(float f) {
  union { __hip_bfloat16 h; unsigned short u; } cv;
  cv.h = __float2bfloat16(f);
  return cv.u;
}
static __device__ __forceinline__ float bflo(unsigned int u) { return __uint_as_float(u << 16); }
static __device__ __forceinline__ float bfhi(unsigned int u) { return __uint_as_float(u & 0xffff0000u); }

// ---------------- pack weights into MFMA B-fragment order (bf16) ----------------
// B[k][n] = (n < nsplit ? Wa[n][k] : Wb[n-nsplit][k]); layout:
// dst[((ktile*NT + ntile)*64 + lane)*8 + j] = B[ktile*32 + (lane>>4)*8 + j][ntile*16 + (lane&15)]
__global__ void pack_b_kernel(const float* __restrict__ Wa, const float* __restrict__ Wb,
                              int nsplit, int Kd, int Nd, unsigned short* __restrict__ dst) {
  int tid = blockIdx.x * blockDim.x + threadIdx.x;
  int total = Kd * Nd;
  if (tid >= total) return;
  int j    = tid & 7;
  int lane = (tid >> 3) & 63;
  int t2   = tid >> 9;            // ktile*NT + ntile
  int NT   = Nd >> 4;
  int ntile = t2 % NT;
  int ktile = t2 / NT;
  int k = ktile * 32 + (lane >> 4) * 8 + j;
  int n = ntile * 16 + (lane & 15);
  float v = (n < nsplit) ? Wa[(size_t)n * Kd + k] : Wb[(size_t)(n - nsplit) * Kd + k];
  dst[tid] = f2bf_bits(v);
}

// ---------------- generic MFMA GEMM: OUT[M][NT*16] = bf16(A[M][KD]) @ Bpack ----------------
// EPI 0: store bf16.  EPI 1: relu(x + bias) -> fp32.  EPI 2: x + bias + resid, LayerNorm -> fp32.
template<int KD, int NT, int EPI>
__global__ __launch_bounds__(256) void gemm_k(
    const float* __restrict__ A, const unsigned short* __restrict__ Bp, int M,
    unsigned short* __restrict__ outb, float* __restrict__ outf,
    const float* __restrict__ bias, const float* __restrict__ resid,
    const float* __restrict__ gamma, const float* __restrict__ beta) {
  constexpr int ND = NT * 16;
  const int l    = threadIdx.x & 63;
  const int w    = threadIdx.x >> 6;
  const int quad = l >> 4;
  const int col0 = l & 15;
  const int row0 = blockIdx.x * 64 + w * 16;
  int arow = row0 + col0;                 // A-frag row: m = lane&15
  if (arow >= M) arow = M - 1;

  floatx4 acc[NT];
#pragma unroll
  for (int i = 0; i < NT; i++) acc[i] = (floatx4){0.f, 0.f, 0.f, 0.f};

  const float* aptr = A + (size_t)arow * KD + quad * 8;
#pragma unroll
  for (int k0 = 0; k0 < KD; k0 += 32) {
    floatx4 a0 = *(const floatx4*)(aptr + k0);
    floatx4 a1 = *(const floatx4*)(aptr + k0 + 4);
    short8 af;
    af[0] = (short)f2bf_bits(a0[0]); af[1] = (short)f2bf_bits(a0[1]);
    af[2] = (short)f2bf_bits(a0[2]); af[3] = (short)f2bf_bits(a0[3]);
    af[4] = (short)f2bf_bits(a1[0]); af[5] = (short)f2bf_bits(a1[1]);
    af[6] = (short)f2bf_bits(a1[2]); af[7] = (short)f2bf_bits(a1[3]);
    const unsigned short* bbase = Bp + (size_t)(k0 >> 5) * NT * 512 + l * 8;
#pragma unroll
    for (int nt = 0; nt < NT; nt++) {
      short8 bf = *(const short8*)(bbase + nt * 512);
      acc[nt] = __builtin_amdgcn_mfma_f32_16x16x32_bf16(af, bf, acc[nt], 0, 0, 0);
    }
  }

  if (EPI == 0) {
#pragma unroll
    for (int nt = 0; nt < NT; nt++) {
#pragma unroll
      for (int r = 0; r < 4; r++) {
        int row = row0 + quad * 4 + r;    // C/D: row = (lane>>4)*4 + reg, col = lane&15
        if (row < M) outb[(size_t)row * ND + nt * 16 + col0] = f2bf_bits(acc[nt][r]);
      }
    }
  } else if (EPI == 1) {
#pragma unroll
    for (int nt = 0; nt < NT; nt++) {
#pragma unroll
      for (int r = 0; r < 4; r++) {
        int row = row0 + quad * 4 + r;
        if (row < M) {
          int c = nt * 16 + col0;
          float v = acc[nt][r] + bias[c];
          outf[(size_t)row * ND + c] = fmaxf(v, 0.f);
        }
      }
    }
  } else {
    // ND must be 128 here (NT==8)
#pragma unroll
    for (int r = 0; r < 4; r++) {
      int row = row0 + quad * 4 + r;
      int rr  = row < M ? row : M - 1;
      float v[NT];
      float s1 = 0.f, s2 = 0.f;
#pragma unroll
      for (int nt = 0; nt < NT; nt++) {
        int c = nt * 16 + col0;
        v[nt] = acc[nt][r] + bias[c] + resid[(size_t)rr * ND + c];
        s1 += v[nt];
      }
      s1 += __shfl_xor(s1, 1, 64); s1 += __shfl_xor(s1, 2, 64);
      s1 += __shfl_xor(s1, 4, 64); s1 += __shfl_xor(s1, 8, 64);
#pragma unroll
      for (int nt = 0; nt < NT; nt++) s2 += v[nt] * v[nt];
      s2 += __shfl_xor(s2, 1, 64); s2 += __shfl_xor(s2, 2, 64);
      s2 += __shfl_xor(s2, 4, 64); s2 += __shfl_xor(s2, 8, 64);
      float mean = s1 * (1.0f / ND);
      float var  = s2 * (1.0f / ND) - mean * mean;
      float rstd = rsqrtf(var + 1e-5f);
      if (row < M) {
#pragma unroll
        for (int nt = 0; nt < NT; nt++) {
          int c = nt * 16 + col0;
          outf[(size_t)row * ND + c] = (v[nt] - mean) * rstd * gamma[c] + beta[c];
        }
      }
    }
  }
}

// ---------------- attention: one wave per query, online softmax, no LDS ----------------
__global__ __launch_bounds__(256) void attn_kernel(
    const unsigned short* __restrict__ Qb,    // [N_QUERY][128] bf16
    const unsigned short* __restrict__ KVb,   // [N_ATOM][256] bf16 (K | V)
    const float* __restrict__ edge_attr,      // [E][16]
    const float* __restrict__ Wrbf,           // [8][16]
    const int* __restrict__ src,              // [E]
    const float* __restrict__ h_query,        // [N_QUERY][128]
    float* __restrict__ Z) {                  // [N_QUERY][256] = [h_query | agg]
  const int l = threadIdx.x & 63;
  const int w = threadIdx.x >> 6;
  const int q = blockIdx.x * 4 + w;
  const int h  = l >> 3;          // head of dims 2l,2l+1  (2l/16 == l/8)
  const int r8 = l & 7;

  unsigned int qu = ((const unsigned int*)(Qb + (size_t)q * 128))[l];
  float q0 = bflo(qu) * 0.25f;    // 1/sqrt(16) folded into Q
  float q1 = bfhi(qu) * 0.25f;
  float2 wr = *(const float2*)(Wrbf + h * 16 + 2 * r8);

  const int e0 = q * KNN;
  int srcj = (l < KNN) ? src[e0 + l] : 0;

  float m = -1e30f, lsum = 0.f, acc0 = 0.f, acc1 = 0.f;
#pragma unroll 8
  for (int j = 0; j < KNN; j++) {
    int s = __shfl(srcj, j, 64);
    const unsigned int* kvp = (const unsigned int*)(KVb + (size_t)s * 256);
    unsigned int ku = kvp[l];
    unsigned int vu = kvp[64 + l];
    float2 ea = *(const float2*)(edge_attr + (size_t)(e0 + j) * 16 + 2 * r8);
    float part = q0 * bflo(ku) + q1 * bfhi(ku) + wr.x * ea.x + wr.y * ea.y;
    part += __shfl_xor(part, 1, 64);
    part += __shfl_xor(part, 2, 64);
    part += __shfl_xor(part, 4, 64);   // all 8 lanes of the head group hold score[j][h]
    float mn = fmaxf(m, part);
    float p  = __expf(part - mn);
    float sc = __expf(m - mn);
    lsum = lsum * sc + p;
    acc0 = acc0 * sc + p * bflo(vu);
    acc1 = acc1 * sc + p * bfhi(vu);
    m = mn;
  }
  float inv = 1.f / (lsum + 1e-16f);
  float* zrow = Z + (size_t)q * 256;
  float2 hq = *(const float2*)(h_query + (size_t)q * 128 + 2 * l);
  *(float2*)(zrow + 2 * l) = hq;
  float2 ag; ag.x = acc0 * inv; ag.y = acc1 * inv;
  *(float2*)(zrow + 128 + 2 * l) = ag;
}

extern "C" void kernel_launch(void* const* d_in, const int* in_sizes, int n_in,
                              void* d_out, int out_size, void* d_ws, size_t ws_size,
                              hipStream_t stream) {
  const float* h_atom    = (const float*)d_in[0];
  const float* h_query   = (const float*)d_in[1];
  const float* edge_attr = (const float*)d_in[2];
  const float* W_q  = (const float*)d_in[3];
  const float* W_k  = (const float*)d_in[4];
  const float* W_v  = (const float*)d_in[5];
  const float* Wrbf = (const float*)d_in[6];
  const float* W1   = (const float*)d_in[7];
  const float* b1   = (const float*)d_in[8];
  const float* W2   = (const float*)d_in[9];
  const float* b2   = (const float*)d_in[10];
  const float* ln_g = (const float*)d_in[11];
  const float* ln_b = (const float*)d_in[12];
  const int* edge_index = (const int*)d_in[13];   // [0..E) = src
  float* out = (float*)d_out;

  char* ws = (char*)d_ws;
  unsigned short* KVb = (unsigned short*)(ws);                 // 100000*256 bf16 = 51.2 MB
  unsigned short* Qb  = (unsigned short*)(ws + 51200000);      // 20000*128 bf16 = 5.12 MB
  float* Zbuf = (float*)(ws + 56320000);                       // 20000*256 f32  = 20.48 MB
  float* Hbuf = (float*)(ws + 76800000);                       // 20000*128 f32  = 10.24 MB
  unsigned short* WKVp = (unsigned short*)(ws + 87040000);     // 128x256
  unsigned short* WQp  = WKVp + 32768;                         // 128x128
  unsigned short* W1p  = WQp  + 16384;                         // 256x128
  unsigned short* W2p  = W1p  + 32768;                         // 128x128

  // pack weights (B = W^T in frag order); WKV fuses [W_k | W_v] -> N=256
  pack_b_kernel<<<(32768 + 255) / 256, 256, 0, stream>>>(W_k, W_v, 128, 128, 256, WKVp);
  pack_b_kernel<<<(16384 + 255) / 256, 256, 0, stream>>>(W_q, W_q, 128, 128, 128, WQp);
  pack_b_kernel<<<(32768 + 255) / 256, 256, 0, stream>>>(W1, W1, 128, 256, 128, W1p);
  pack_b_kernel<<<(16384 + 255) / 256, 256, 0, stream>>>(W2, W2, 128, 128, 128, W2p);

  // KV = h_atom @ [W_k|W_v]^T  -> bf16 [N_ATOM][256]
  gemm_k<128, 16, 0><<<(N_ATOM + 63) / 64, 256, 0, stream>>>(
      h_atom, WKVp, N_ATOM, KVb, nullptr, nullptr, nullptr, nullptr, nullptr);
  // Q = h_query @ W_q^T -> bf16 [N_QUERY][128]
  gemm_k<128, 8, 0><<<(N_QUERY + 63) / 64, 256, 0, stream>>>(
      h_query, WQp, N_QUERY, Qb, nullptr, nullptr, nullptr, nullptr, nullptr);
  // attention -> Zbuf = [h_query | agg]
  attn_kernel<<<N_QUERY / 4, 256, 0, stream>>>(Qb, KVb, edge_attr, Wrbf, edge_index, h_query, Zbuf);
  // hidden = relu(Z @ W1^T + b1) -> fp32
  gemm_k<256, 8, 1><<<(N_QUERY + 63) / 64, 256, 0, stream>>>(
      Zbuf, W1p, N_QUERY, nullptr, Hbuf, b1, nullptr, nullptr, nullptr);
  // out = LN(hidden @ W2^T + b2 + h_query)
  gemm_k<128, 8, 2><<<(N_QUERY + 63) / 64, 256, 0, stream>>>(
      Hbuf, W2p, N_QUERY, nullptr, out, b2, h_query, ln_g, ln_b);
}